// Round 1
// baseline (1392.000 us; speedup 1.0000x reference)
//
#include <hip/hip_runtime.h>
#include <math.h>

#define B_ 2048
#define S_ 512
#define H_ 256
#define F_ 64
#define KA (H_ + F_)   // 320
#define G3 (3 * H_)    // 768

// ---------------- GEMM tile config (shared by logits + GRU GEMM) -----------
#define BM 64
#define BN 64
#define BK 32
#define LDA (BM + 4)   // pad 4 keeps 16B alignment for b128 reads, breaks store conflicts

// ---- Kernel 1: logits[b,s] = concat(h_prev,y)[b,:] . attn_W[s,:] + attn_b[s]
__global__ __launch_bounds__(256)
void attn_logits_kernel(const float* __restrict__ hprev, const float* __restrict__ y,
                        const float* __restrict__ W, const float* __restrict__ bias,
                        float* __restrict__ logits) {
    __shared__ float As[BK][LDA];
    __shared__ float Ws[BK][LDA];
    const int m0 = blockIdx.x * BM;
    const int n0 = blockIdx.y * BN;
    const int tid = threadIdx.x;
    const int tn = tid & 15, tm = tid >> 4;
    float acc[4][4] = {};
    for (int k0 = 0; k0 < KA; k0 += BK) {
#pragma unroll
        for (int i = 0; i < 2; ++i) {
            int idx = tid + i * 256;       // 0..511
            int r = idx >> 3;              // tile row 0..63
            int k = (idx & 7) << 2;        // k offset 0,4,...,28
            int gk = k0 + k;
            float4 a4;
            if (gk < H_) a4 = *(const float4*)(hprev + (size_t)(m0 + r) * H_ + gk);
            else         a4 = *(const float4*)(y + (size_t)(m0 + r) * F_ + (gk - H_));
            As[k + 0][r] = a4.x; As[k + 1][r] = a4.y; As[k + 2][r] = a4.z; As[k + 3][r] = a4.w;
            float4 w4 = *(const float4*)(W + (size_t)(n0 + r) * KA + gk);
            Ws[k + 0][r] = w4.x; Ws[k + 1][r] = w4.y; Ws[k + 2][r] = w4.z; Ws[k + 3][r] = w4.w;
        }
        __syncthreads();
#pragma unroll
        for (int k = 0; k < BK; ++k) {
            float4 a = *(const float4*)&As[k][tm << 2];
            float4 w = *(const float4*)&Ws[k][tn << 2];
            float av[4] = {a.x, a.y, a.z, a.w};
            float wv[4] = {w.x, w.y, w.z, w.w};
#pragma unroll
            for (int i = 0; i < 4; ++i)
#pragma unroll
                for (int j = 0; j < 4; ++j)
                    acc[i][j] = fmaf(av[i], wv[j], acc[i][j]);
        }
        __syncthreads();
    }
#pragma unroll
    for (int i = 0; i < 4; ++i) {
        int m = m0 + (tm << 2) + i;
        int n = n0 + (tn << 2);
        float4 o;
        o.x = acc[i][0] + bias[n + 0];
        o.y = acc[i][1] + bias[n + 1];
        o.z = acc[i][2] + bias[n + 2];
        o.w = acc[i][3] + bias[n + 3];
        *(float4*)(logits + (size_t)m * S_ + n) = o;
    }
}

// ---- Kernel 2: in-place softmax over rows of [B_, S_]
__global__ __launch_bounds__(256)
void softmax_kernel(float* __restrict__ wts) {
    __shared__ float red[16];
    const int b = blockIdx.x;
    const int tid = threadIdx.x;
    float* row = wts + (size_t)b * S_;
    float v0 = row[tid], v1 = row[tid + 256];
    float m = fmaxf(v0, v1);
#pragma unroll
    for (int off = 32; off > 0; off >>= 1) m = fmaxf(m, __shfl_down(m, off, 64));
    if ((tid & 63) == 0) red[tid >> 6] = m;
    __syncthreads();
    if (tid == 0) red[4] = fmaxf(fmaxf(red[0], red[1]), fmaxf(red[2], red[3]));
    __syncthreads();
    m = red[4];
    float e0 = expf(v0 - m), e1 = expf(v1 - m);
    float s = e0 + e1;
#pragma unroll
    for (int off = 32; off > 0; off >>= 1) s += __shfl_down(s, off, 64);
    if ((tid & 63) == 0) red[8 + (tid >> 6)] = s;
    __syncthreads();
    if (tid == 0) red[12] = red[8] + red[9] + red[10] + red[11];
    __syncthreads();
    float inv = 1.0f / red[12];
    row[tid] = e0 * inv;
    row[tid + 256] = e1 * inv;
}

// ---- Kernel 3: ctx[b,h] = sum_s w[b,s] * enc[b,s,h]   (the 1 GiB stream)
__global__ __launch_bounds__(256)
void ctx_kernel(const float* __restrict__ wts, const float* __restrict__ enc,
                float* __restrict__ ctx) {
    __shared__ float w[S_];
    __shared__ float4 red[256];
    const int b = blockIdx.x;
    const int tid = threadIdx.x;
    w[tid] = wts[(size_t)b * S_ + tid];
    w[tid + 256] = wts[(size_t)b * S_ + tid + 256];
    __syncthreads();
    const int q = tid & 63;    // float4 index over H (64 float4 = 256 floats)
    const int sg = tid >> 6;   // 0..3 : s-phase
    const float4* e4 = (const float4*)enc + ((size_t)b * S_ + sg) * 64 + q;
    float4 acc = {0.f, 0.f, 0.f, 0.f};
#pragma unroll 8
    for (int s = sg; s < S_; s += 4) {
        float ws = w[s];
        float4 v = *e4;
        acc.x = fmaf(ws, v.x, acc.x);
        acc.y = fmaf(ws, v.y, acc.y);
        acc.z = fmaf(ws, v.z, acc.z);
        acc.w = fmaf(ws, v.w, acc.w);
        e4 += 4 * 64;
    }
    red[tid] = acc;
    __syncthreads();
    if (tid < 64) {
        float4 a = red[tid], b1 = red[tid + 64], c = red[tid + 128], d = red[tid + 192];
        float4 r;
        r.x = (a.x + b1.x) + (c.x + d.x);
        r.y = (a.y + b1.y) + (c.y + d.y);
        r.z = (a.z + b1.z) + (c.z + d.z);
        r.w = (a.w + b1.w) + (c.w + d.w);
        *((float4*)ctx + (size_t)b * 64 + tid) = r;
    }
}

// ---- Kernel 4: g[b, 0:768] = ctx @ W_ih^T + b_ih ; g[b, 768:1536] = h @ W_hh^T + b_hh
__global__ __launch_bounds__(256)
void gru_gemm_kernel(const float* __restrict__ ctx, const float* __restrict__ hprev,
                     const float* __restrict__ Wih, const float* __restrict__ Whh,
                     const float* __restrict__ bih, const float* __restrict__ bhh,
                     float* __restrict__ g) {
    __shared__ float As[BK][LDA];
    __shared__ float Ws[BK][LDA];
    const int m0 = blockIdx.x * BM;
    const int n0 = blockIdx.y * BN;           // 0..1472
    const bool hh = (n0 >= G3);
    const float* A = hh ? hprev : ctx;
    const float* W = hh ? Whh : Wih;
    const float* bias = hh ? bhh : bih;
    const int nb = hh ? (n0 - G3) : n0;
    const int tid = threadIdx.x;
    const int tn = tid & 15, tm = tid >> 4;
    float acc[4][4] = {};
    for (int k0 = 0; k0 < H_; k0 += BK) {
#pragma unroll
        for (int i = 0; i < 2; ++i) {
            int idx = tid + i * 256;
            int r = idx >> 3;
            int k = (idx & 7) << 2;
            int gk = k0 + k;
            float4 a4 = *(const float4*)(A + (size_t)(m0 + r) * H_ + gk);
            As[k + 0][r] = a4.x; As[k + 1][r] = a4.y; As[k + 2][r] = a4.z; As[k + 3][r] = a4.w;
            float4 w4 = *(const float4*)(W + (size_t)(nb + r) * H_ + gk);
            Ws[k + 0][r] = w4.x; Ws[k + 1][r] = w4.y; Ws[k + 2][r] = w4.z; Ws[k + 3][r] = w4.w;
        }
        __syncthreads();
#pragma unroll
        for (int k = 0; k < BK; ++k) {
            float4 a = *(const float4*)&As[k][tm << 2];
            float4 w = *(const float4*)&Ws[k][tn << 2];
            float av[4] = {a.x, a.y, a.z, a.w};
            float wv[4] = {w.x, w.y, w.z, w.w};
#pragma unroll
            for (int i = 0; i < 4; ++i)
#pragma unroll
                for (int j = 0; j < 4; ++j)
                    acc[i][j] = fmaf(av[i], wv[j], acc[i][j]);
        }
        __syncthreads();
    }
#pragma unroll
    for (int i = 0; i < 4; ++i) {
        int m = m0 + (tm << 2) + i;
        int nl = (tn << 2);
        float4 o;
        o.x = acc[i][0] + bias[nb + nl + 0];
        o.y = acc[i][1] + bias[nb + nl + 1];
        o.z = acc[i][2] + bias[nb + nl + 2];
        o.w = acc[i][3] + bias[nb + nl + 3];
        *(float4*)(g + (size_t)m * 1536 + n0 + nl) = o;
    }
}

// ---- Kernel 5: gates, h_new, and out = h_new . out_W + out_b
__global__ __launch_bounds__(256)
void gate_kernel(const float* __restrict__ g, const float* __restrict__ hprev,
                 const float* __restrict__ outW, const float* __restrict__ outb,
                 float* __restrict__ out) {
    __shared__ float red[4];
    const int b = blockIdx.x;
    const int tid = threadIdx.x;
    const float* gr = g + (size_t)b * 1536;
    float ir = gr[tid], iz = gr[tid + 256], in_ = gr[tid + 512];
    float hr = gr[tid + 768], hz = gr[tid + 1024], hn = gr[tid + 1280];
    float hp = hprev[(size_t)b * H_ + tid];
    float r = 1.f / (1.f + expf(-(ir + hr)));
    float z = 1.f / (1.f + expf(-(iz + hz)));
    float n = tanhf(in_ + r * hn);
    float hnew = (1.f - z) * n + z * hp;
    out[B_ + (size_t)b * H_ + tid] = hnew;
    float p = hnew * outW[tid];
#pragma unroll
    for (int off = 32; off > 0; off >>= 1) p += __shfl_down(p, off, 64);
    if ((tid & 63) == 0) red[tid >> 6] = p;
    __syncthreads();
    if (tid == 0) out[b] = (red[0] + red[1]) + (red[2] + red[3]) + outb[0];
}

extern "C" void kernel_launch(void* const* d_in, const int* in_sizes, int n_in,
                              void* d_out, int out_size, void* d_ws, size_t ws_size,
                              hipStream_t stream) {
    (void)in_sizes; (void)n_in; (void)out_size; (void)ws_size;
    const float* enc    = (const float*)d_in[0];
    const float* hprev  = (const float*)d_in[1];
    const float* y      = (const float*)d_in[2];
    const float* attn_W = (const float*)d_in[3];
    const float* attn_b = (const float*)d_in[4];
    const float* W_ih   = (const float*)d_in[5];
    const float* W_hh   = (const float*)d_in[6];
    const float* b_ih   = (const float*)d_in[7];
    const float* b_hh   = (const float*)d_in[8];
    const float* out_W  = (const float*)d_in[9];
    const float* out_b  = (const float*)d_in[10];
    float* out = (float*)d_out;

    float* ws     = (float*)d_ws;
    float* logits = ws;                              // B*S   = 1,048,576 f
    float* ctx    = logits + (size_t)B_ * S_;        // B*H   =   524,288 f
    float* g      = ctx + (size_t)B_ * H_;           // B*3H*2= 3,145,728 f

    attn_logits_kernel<<<dim3(B_ / BM, S_ / BN), 256, 0, stream>>>(hprev, y, attn_W, attn_b, logits);
    softmax_kernel<<<B_, 256, 0, stream>>>(logits);
    ctx_kernel<<<B_, 256, 0, stream>>>(logits, enc, ctx);
    gru_gemm_kernel<<<dim3(B_ / BM, 1536 / BN), 256, 0, stream>>>(ctx, hprev, W_ih, W_hh, b_ih, b_hh, g);
    gate_kernel<<<B_, 256, 0, stream>>>(g, hprev, out_W, out_b, out);
}